// Round 10
// baseline (420.708 us; speedup 1.0000x reference)
//
#include <hip/hip_runtime.h>

#define FIN 128
#define FHID 32
#define FOUT 64
#define MAXDEG 10
#define BSH 8              // dst bucket = dst >> 8 (256 dsts per bucket)
#define ACHUNK 4096        // edges per pass-A workgroup (16 per thread)
#define XPAD 136           // LDS row stride (bf16) for 128-k tiles
#define YPAD 40            // LDS row stride (bf16) for 32-k tiles

typedef __attribute__((ext_vector_type(8))) short short8;
typedef __attribute__((ext_vector_type(4))) float f32x4;

// edge_index arrives as int32 (harness converts integer inputs to int):
// layout [2, E] flat: src = ei[e], dst = ei[E + e].

__device__ __forceinline__ float bf2f(unsigned short u) {
    union { unsigned int i; float f; } c; c.i = ((unsigned int)u) << 16; return c.f;
}
__device__ __forceinline__ unsigned short f2bf(float f) {
    union { float f; unsigned int i; } c; c.f = f;
    unsigned int r = c.i + 0x7FFF + ((c.i >> 16) & 1);   // round-nearest-even
    return (unsigned short)(r >> 16);
}
__device__ __forceinline__ float bflo(unsigned int w) { return bf2f((unsigned short)(w & 0xffff)); }
__device__ __forceinline__ float bfhi(unsigned int w) { return bf2f((unsigned short)(w >> 16)); }

// ---- self-consistent software fp8 (s|e4|m3, bias 7, linear-decodable) ----
// decode(u) = as_float(((u&0x80)<<24) | ((u&0x7F)<<20)) * 2^120  — linear in the
// reinterpreted float, so gather kernels accumulate RAW values and scale once.
__device__ __forceinline__ float fp8raw(unsigned int w, int i) {
    unsigned int t = (w >> (i * 8)) & 0xffu;
    union { unsigned int i; float f; } c;
    c.i = ((t & 0x80u) << 24) | ((t & 0x7fu) << 20);
    return c.f;                         // value * 2^-120
}
__device__ __forceinline__ unsigned char f2fp8(float v) {
    union { float f; unsigned int i; } c; c.f = v * 0x1p-120f;
    unsigned int b = c.i;
    unsigned int r = b + 0x7FFFFu + ((b >> 20) & 1u);   // RNE on 20-bit truncation
    return (unsigned char)(((r >> 24) & 0x80u) | ((r >> 20) & 0x7fu));
}

// ---------- CSR build ----------

__global__ __launch_bounds__(256) void k_count(const int* __restrict__ ei, int E, int N,
                                               int* __restrict__ deg) {
    int e = blockIdx.x * 256 + threadIdx.x;
    if (e >= E) return;
    int d = ei[E + e];
    if ((unsigned)d < (unsigned)N) atomicAdd(deg + d, 1);
}

__global__ __launch_bounds__(256) void k_blocksum(const int* __restrict__ deg, int N,
                                                  int* __restrict__ partial) {
    __shared__ int tmp[256];
    int t = threadIdx.x;
    int i = blockIdx.x * 256 + t;
    tmp[t] = (i < N) ? deg[i] : 0;
    __syncthreads();
    for (int off = 128; off > 0; off >>= 1) {
        if (t < off) tmp[t] += tmp[t + off];
        __syncthreads();
    }
    if (t == 0) partial[blockIdx.x] = tmp[0];
}

__global__ __launch_bounds__(1024) void k_scanpartial(const int* __restrict__ partial, int NB,
                                                      int* __restrict__ offsets) {
    __shared__ int tmp[1024];
    int t = threadIdx.x;
    int v = (t < NB) ? partial[t] : 0;
    tmp[t] = v;
    __syncthreads();
    for (int off = 1; off < 1024; off <<= 1) {
        int a = (t >= off) ? tmp[t - off] : 0;
        __syncthreads();
        tmp[t] += a;
        __syncthreads();
    }
    if (t < NB) offsets[t] = tmp[t] - v;
}

__global__ __launch_bounds__(256) void k_scandeg(const int* __restrict__ deg, int N,
                                                 const int* __restrict__ offsets,
                                                 int* __restrict__ cursor) {
    __shared__ int tmp[256];
    int t = threadIdx.x;
    int i = blockIdx.x * 256 + t;
    int v = (i < N) ? deg[i] : 0;
    tmp[t] = v;
    __syncthreads();
    for (int off = 1; off < 256; off <<= 1) {
        int a = (t >= off) ? tmp[t - off] : 0;
        __syncthreads();
        tmp[t] += a;
        __syncthreads();
    }
    if (i < N) cursor[i] = offsets[blockIdx.x] + tmp[t] - v;
}

__global__ __launch_bounds__(256) void k_initb(const int* __restrict__ cursor,
                                               int* __restrict__ gcur, int K) {
    int b = blockIdx.x * 256 + threadIdx.x;
    if (b < K) gcur[b] = cursor[b << BSH];
}

// Pass A: bucket edges by dst>>8 into pairs[], line-coalesced appends.
__global__ __launch_bounds__(256) void k_passA(const int* __restrict__ ei, int E, int N,
                                               int* __restrict__ gcur,
                                               int2* __restrict__ pairs) {
    __shared__ int hist[1024];
    __shared__ int base[1024];
    int K = ((N + 255) >> BSH);
    int t = threadIdx.x;
    long long cb = (long long)blockIdx.x * ACHUNK;
    for (int i = t; i < K; i += 256) hist[i] = 0;
    __syncthreads();
    int sv[16], dv[16];
#pragma unroll
    for (int i = 0; i < 16; ++i) {
        sv[i] = -1; dv[i] = 0;
        long long e = cb + t + (long long)i * 256;
        if (e < E) {
            int ss = ei[e];
            int dd = ei[E + e];
            if ((unsigned)ss < (unsigned)N && (unsigned)dd < (unsigned)N) {
                sv[i] = ss; dv[i] = dd;
            }
        }
    }
#pragma unroll
    for (int i = 0; i < 16; ++i)
        if (sv[i] >= 0) atomicAdd(&hist[dv[i] >> BSH], 1);
    __syncthreads();
    for (int i = t; i < K; i += 256) {
        int h = hist[i];
        base[i] = h ? atomicAdd(&gcur[i], h) : 0;
    }
    __syncthreads();
    for (int i = t; i < K; i += 256) hist[i] = 0;
    __syncthreads();
#pragma unroll
    for (int i = 0; i < 16; ++i) {
        if (sv[i] >= 0) {
            int b = dv[i] >> BSH;
            int off = atomicAdd(&hist[b], 1);
            pairs[base[b] + off] = make_int2(sv[i], dv[i]);
        }
    }
}

// Pass B: one workgroup per bucket; private LDS cursors; flushes row ends.
__global__ __launch_bounds__(256) void k_passB(const int2* __restrict__ pairs,
                                               const int* __restrict__ gcur,
                                               int* __restrict__ cursor,
                                               int* __restrict__ adj, int N) {
    __shared__ int cur[256];
    int b = blockIdx.x;
    int lo = b << BSH;
    int hi = min(lo + 256, N);
    int t = threadIdx.x;
    int cnt = hi - lo;
    if (t < cnt) cur[t] = cursor[lo + t];
    int pstart = cursor[lo];
    int pend = gcur[b];
    __syncthreads();
    for (int i = pstart + t; i < pend; i += 256) {
        int2 pr = pairs[i];
        int pos = atomicAdd(&cur[pr.y - lo], 1);
        adj[pos] = pr.x;
    }
    __syncthreads();
    if (t < cnt) cursor[lo + t] = cur[t];
}

// ---------- prepack bucket-10 weights as bf16, B-operand layout [n][k] ----------
__global__ __launch_bounds__(256) void k_prepack(const float* __restrict__ W1,
                                                 const float* __restrict__ Wr1,
                                                 const float* __restrict__ W2,
                                                 const float* __restrict__ Wr2,
                                                 unsigned short* __restrict__ wcat1,
                                                 unsigned short* __restrict__ wcat2) {
    int t = threadIdx.x;
    const float* W1b  = W1  + (size_t)MAXDEG * FIN * FHID;
    const float* Wr1b = Wr1 + (size_t)MAXDEG * FIN * FHID;
    const float* W2b  = W2  + (size_t)MAXDEG * FHID * FOUT;
    const float* Wr2b = Wr2 + (size_t)MAXDEG * FHID * FOUT;
    for (int i = 0; i < 32; ++i) {
        int idx = i * 256 + t;            // 8192
        int n = idx >> 7, k = idx & 127;
        float v = (n < 32) ? W1b[k * FHID + n] : Wr1b[k * FHID + (n - 32)];
        wcat1[idx] = f2bf(v);
    }
    for (int i = 0; i < 16; ++i) {
        int idx = i * 256 + t;            // 4096
        int n = idx >> 5, k = idx & 31;
        float v = (n < 64) ? W2b[k * FOUT + n] : Wr2b[k * FOUT + (n - 64)];
        wcat2[idx] = f2bf(v);
    }
}

// ---------- pre1 (MFMA): [z8 | r1] = x @ [W1[10] | Wr1[10]] + [0 | b1[10]] ----------
__global__ __launch_bounds__(256) void k_pre1m(const float* __restrict__ x,
                                               const unsigned short* __restrict__ wcat1,
                                               const float* __restrict__ b1,
                                               unsigned char* __restrict__ z8,
                                               unsigned short* __restrict__ r1, int N) {
    __shared__ __align__(16) unsigned short xt[64 * XPAD];
    __shared__ __align__(16) unsigned short wt[64 * XPAD];
    int t = threadIdx.x;
    int row0 = blockIdx.x * 64;
    {   // stage Wcat1 (8192 bf16 = 1024 uint4)
        const uint4* src = (const uint4*)wcat1;
#pragma unroll
        for (int i = 0; i < 4; ++i) {
            int idx = i * 256 + t;
            uint4 v = src[idx];
            int n = idx >> 4;
            int k = (idx & 15) * 8;
            *(uint4*)(wt + n * XPAD + k) = v;
        }
    }
    {   // stage x rows -> bf16
        int r = t >> 2;
        int c0 = (t & 3) * 32;
        int cr = min(row0 + r, N - 1);
        const float4* xs = (const float4*)(x + (size_t)cr * FIN + c0);
        unsigned short* dst = xt + r * XPAD + c0;
#pragma unroll
        for (int i = 0; i < 8; ++i) {
            float4 v = xs[i];
            ushort4 b;
            b.x = f2bf(v.x); b.y = f2bf(v.y); b.z = f2bf(v.z); b.w = f2bf(v.w);
            *(ushort4*)(dst + i * 4) = b;
        }
    }
    __syncthreads();
    int w = t >> 6, lane = t & 63;
    int m = lane & 15, quad = lane >> 4;
    const unsigned short* arow = xt + (w * 16 + m) * XPAD + quad * 8;
    short8 af[4];
#pragma unroll
    for (int kt = 0; kt < 4; ++kt) af[kt] = *(const short8*)(arow + kt * 32);
    f32x4 acc[4];
#pragma unroll
    for (int ct = 0; ct < 4; ++ct) acc[ct] = (f32x4){0.f, 0.f, 0.f, 0.f};
#pragma unroll
    for (int ct = 0; ct < 4; ++ct) {
        const unsigned short* brow = wt + (ct * 16 + m) * XPAD + quad * 8;
#pragma unroll
        for (int kt = 0; kt < 4; ++kt) {
            short8 bfr = *(const short8*)(brow + kt * 32);
            acc[ct] = __builtin_amdgcn_mfma_f32_16x16x32_bf16(af[kt], bfr, acc[ct], 0, 0, 0);
        }
    }
    int rbase = row0 + w * 16 + quad * 4;
#pragma unroll
    for (int ct = 0; ct < 4; ++ct) {
        float bias = (ct >= 2) ? b1[MAXDEG * FHID + (ct - 2) * 16 + m] : 0.f;
#pragma unroll
        for (int rg = 0; rg < 4; ++rg) {
            int n = rbase + rg;
            if (n < N) {
                float v = acc[ct][rg];
                if (ct < 2) z8[(size_t)n * FHID + ct * 16 + m] = f2fp8(v);
                else        r1[(size_t)n * FHID + (ct - 2) * 16 + m] = f2bf(v + bias);
            }
        }
    }
}

// ---------- pre2 (MFMA): [p8 | r2] = y @ [W2[10] | Wr2[10]] + [0 | b2[10]] ----------
__global__ __launch_bounds__(256) void k_pre2m(const unsigned short* __restrict__ y,
                                               const unsigned short* __restrict__ wcat2,
                                               const float* __restrict__ b2,
                                               unsigned char* __restrict__ p8,
                                               unsigned short* __restrict__ r2, int N) {
    __shared__ __align__(16) unsigned short yt[64 * YPAD];
    __shared__ __align__(16) unsigned short wt[128 * YPAD];
    int t = threadIdx.x;
    int row0 = blockIdx.x * 64;
    {   // stage wcat2
        const uint4* src = (const uint4*)wcat2;
#pragma unroll
        for (int i = 0; i < 2; ++i) {
            int idx = i * 256 + t;
            uint4 v = src[idx];
            int n = idx >> 2;
            int k = (idx & 3) * 8;
            *(uint4*)(wt + n * YPAD + k) = v;
        }
    }
    {   // stage y rows (already bf16)
        int r = t >> 2, c0 = (t & 3) * 8;
        int cr = min(row0 + r, N - 1);
        uint4 v = *(const uint4*)(y + (size_t)cr * FHID + c0);
        *(uint4*)(yt + r * YPAD + c0) = v;
    }
    __syncthreads();
    int w = t >> 6, lane = t & 63;
    int m = lane & 15, quad = lane >> 4;
    short8 af = *(const short8*)(yt + (w * 16 + m) * YPAD + quad * 8);
    int rbase = row0 + w * 16 + quad * 4;
#pragma unroll
    for (int ct = 0; ct < 8; ++ct) {
        short8 bfr = *(const short8*)(wt + (ct * 16 + m) * YPAD + quad * 8);
        f32x4 acc = (f32x4){0.f, 0.f, 0.f, 0.f};
        acc = __builtin_amdgcn_mfma_f32_16x16x32_bf16(af, bfr, acc, 0, 0, 0);
        float bias = (ct >= 4) ? b2[MAXDEG * FOUT + (ct - 4) * 16 + m] : 0.f;
#pragma unroll
        for (int rg = 0; rg < 4; ++rg) {
            int n = rbase + rg;
            if (n < N) {
                float v = acc[rg];
                if (ct < 4) p8[(size_t)n * FOUT + ct * 16 + m] = f2fp8(v);
                else        r2[(size_t)n * FOUT + (ct - 4) * 16 + m] = f2bf(v + bias);
            }
        }
    }
}

// fixup: recompute r1 with the node's true bucket for the ~4% deg<10 nodes.
__global__ __launch_bounds__(256) void k_fix1(const float* __restrict__ x,
                                              const int* __restrict__ deg,
                                              const float* __restrict__ b1,
                                              const float* __restrict__ Wr1,
                                              unsigned short* __restrict__ r1, int N) {
    int wavebase = blockIdx.x * 256 + (threadIdx.x & 192);
    int lane = threadIdx.x & 63;
    int nl = wavebase + lane;
    bool fl = (nl < N) && (deg[nl] < MAXDEG);
    unsigned long long mask = __ballot(fl);
    int u = lane >> 5, o = lane & 31;
    while (mask) {
        int b = __ffsll(mask) - 1;
        mask &= mask - 1;
        int n = wavebase + b;
        int d = deg[n];
        const float* Wr = Wr1 + (size_t)d * (FIN * FHID) + o;
        const float4* xr = (const float4*)(x + (size_t)n * FIN);
        float acc = 0.f;
        for (int c = u * 16; c < u * 16 + 16; ++c) {
            float4 xv = xr[c];
            acc += xv.x * Wr[(c * 4 + 0) * FHID] + xv.y * Wr[(c * 4 + 1) * FHID]
                 + xv.z * Wr[(c * 4 + 2) * FHID] + xv.w * Wr[(c * 4 + 3) * FHID];
        }
        acc += __shfl_xor(acc, 32);
        if (lane < 32) r1[(size_t)n * FHID + o] = f2bf(acc + b1[d * FHID + o]);
    }
}

// ---------- layer1: deg>=10 fast path gathers fp8 z8 rows (32 B, L2-resident) ----------
__global__ __launch_bounds__(256) void k_layer1b(const float* __restrict__ x,
                                                 const unsigned char* __restrict__ z8,
                                                 const unsigned short* __restrict__ r1,
                                                 const int* __restrict__ deg,
                                                 const int* __restrict__ cursor,
                                                 const int* __restrict__ adj,
                                                 const float* __restrict__ W1,
                                                 unsigned short* __restrict__ out1, int N) {
    int wave = (int)(((long long)blockIdx.x * 256 + threadIdx.x) >> 6);
    if (wave >= N) return;
    int n = wave;
    int lane = threadIdx.x & 63;
    int dg = deg[n];
    int e1 = cursor[n];
    int e0 = e1 - dg;
    if (dg >= MAXDEG) {
        int g = lane >> 3, l = lane & 7;
        int myk = e0 + lane;
        int sidx = (myk < e1) ? adj[myk] : 0;
        int cnt = min(dg, 64);
        float a0 = 0.f, a1 = 0.f, a2 = 0.f, a3 = 0.f;   // raw (×2^-120) domain
        for (int i = 0; i * 8 < cnt; ++i) {
            int idx = i * 8 + g;
            int s = __shfl(sidx, idx);
            if (idx < cnt) {
                unsigned int w = *(const unsigned int*)(z8 + (size_t)s * FHID + l * 4);
                a0 += fp8raw(w, 0); a1 += fp8raw(w, 1);
                a2 += fp8raw(w, 2); a3 += fp8raw(w, 3);
            }
        }
        for (int k = e0 + 64 + g; k < e1; k += 8) {
            int s = adj[k];
            unsigned int w = *(const unsigned int*)(z8 + (size_t)s * FHID + l * 4);
            a0 += fp8raw(w, 0); a1 += fp8raw(w, 1);
            a2 += fp8raw(w, 2); a3 += fp8raw(w, 3);
        }
#pragma unroll
        for (int m = 8; m <= 32; m <<= 1) {
            a0 += __shfl_xor(a0, m); a1 += __shfl_xor(a1, m);
            a2 += __shfl_xor(a2, m); a3 += __shfl_xor(a3, m);
        }
        if (lane < 8) {
            ushort4 rv = *(const ushort4*)(r1 + (size_t)n * FHID + l * 4);
            ushort4 w;
            w.x = f2bf(fmaxf(a0 * 0x1p120f + bf2f(rv.x), 0.f));
            w.y = f2bf(fmaxf(a1 * 0x1p120f + bf2f(rv.y), 0.f));
            w.z = f2bf(fmaxf(a2 * 0x1p120f + bf2f(rv.z), 0.f));
            w.w = f2bf(fmaxf(a3 * 0x1p120f + bf2f(rv.w), 0.f));
            *(ushort4*)(out1 + (size_t)n * FHID + l * 4) = w;
        }
    } else {
        float2 hs = make_float2(0.f, 0.f);
        for (int k = e0; k < e1; ++k) {
            int s = adj[k];
            float2 v = *(const float2*)(x + (size_t)s * FIN + lane * 2);
            hs.x += v.x; hs.y += v.y;
        }
        int o = lane & 31;
        const float* Wp = W1 + (size_t)dg * (FIN * FHID) + o;
        float acc = 0.f;
#pragma unroll
        for (int f = 0; f < FIN; ++f) {
            float hv = __shfl((f & 1) ? hs.y : hs.x, f >> 1);
            acc += hv * Wp[f * FHID];
        }
        if (lane < 32) {
            float rv = bf2f(r1[(size_t)n * FHID + o]);
            out1[(size_t)n * FHID + o] = f2bf(fmaxf(acc + rv, 0.f));
        }
    }
}

// fixup: recompute r2 with the node's true bucket for deg<10 nodes.
__global__ __launch_bounds__(256) void k_fix2(const unsigned short* __restrict__ y,
                                              const int* __restrict__ deg,
                                              const float* __restrict__ b2,
                                              const float* __restrict__ Wr2,
                                              unsigned short* __restrict__ r2, int N) {
    int wavebase = blockIdx.x * 256 + (threadIdx.x & 192);
    int lane = threadIdx.x & 63;
    int nl = wavebase + lane;
    bool fl = (nl < N) && (deg[nl] < MAXDEG);
    unsigned long long mask = __ballot(fl);
    while (mask) {
        int b = __ffsll(mask) - 1;
        mask &= mask - 1;
        int n = wavebase + b;
        int d = deg[n];
        const float* Wr = Wr2 + (size_t)d * (FHID * FOUT) + lane;
        const uint4* yr = (const uint4*)(y + (size_t)n * FHID);
        float acc = b2[d * FOUT + lane];
        for (int c = 0; c < 4; ++c) {
            uint4 yv = yr[c];
            acc += bflo(yv.x) * Wr[(c * 8 + 0) * FOUT] + bfhi(yv.x) * Wr[(c * 8 + 1) * FOUT]
                 + bflo(yv.y) * Wr[(c * 8 + 2) * FOUT] + bfhi(yv.y) * Wr[(c * 8 + 3) * FOUT]
                 + bflo(yv.z) * Wr[(c * 8 + 4) * FOUT] + bfhi(yv.z) * Wr[(c * 8 + 5) * FOUT]
                 + bflo(yv.w) * Wr[(c * 8 + 6) * FOUT] + bfhi(yv.w) * Wr[(c * 8 + 7) * FOUT];
        }
        r2[(size_t)n * FOUT + lane] = f2bf(acc);
    }
}

// ---------- layer2: deg>=10 fast path gathers fp8 p8 rows (64 B) ----------
__global__ __launch_bounds__(256) void k_layer2b(const unsigned char* __restrict__ p8,
                                                 const unsigned short* __restrict__ r2,
                                                 const unsigned short* __restrict__ y,
                                                 const int* __restrict__ deg,
                                                 const int* __restrict__ cursor,
                                                 const int* __restrict__ adj,
                                                 const float* __restrict__ W2,
                                                 float* __restrict__ out, int N) {
    int wave = (int)(((long long)blockIdx.x * 256 + threadIdx.x) >> 6);
    if (wave >= N) return;
    int n = wave;
    int lane = threadIdx.x & 63;
    int dg = deg[n];
    int e1 = cursor[n];
    int e0 = e1 - dg;
    if (dg >= MAXDEG) {
        int g = lane >> 3, l = lane & 7;
        int myk = e0 + lane;
        int sidx = (myk < e1) ? adj[myk] : 0;
        int cnt = min(dg, 64);
        float a[8];
#pragma unroll
        for (int m = 0; m < 8; ++m) a[m] = 0.f;      // raw (×2^-120) domain
        for (int i = 0; i * 8 < cnt; ++i) {
            int idx = i * 8 + g;
            int s = __shfl(sidx, idx);
            if (idx < cnt) {
                uint2 w = *(const uint2*)(p8 + (size_t)s * FOUT + l * 8);
                a[0] += fp8raw(w.x, 0); a[1] += fp8raw(w.x, 1);
                a[2] += fp8raw(w.x, 2); a[3] += fp8raw(w.x, 3);
                a[4] += fp8raw(w.y, 0); a[5] += fp8raw(w.y, 1);
                a[6] += fp8raw(w.y, 2); a[7] += fp8raw(w.y, 3);
            }
        }
        for (int k = e0 + 64 + g; k < e1; k += 8) {
            int s = adj[k];
            uint2 w = *(const uint2*)(p8 + (size_t)s * FOUT + l * 8);
            a[0] += fp8raw(w.x, 0); a[1] += fp8raw(w.x, 1);
            a[2] += fp8raw(w.x, 2); a[3] += fp8raw(w.x, 3);
            a[4] += fp8raw(w.y, 0); a[5] += fp8raw(w.y, 1);
            a[6] += fp8raw(w.y, 2); a[7] += fp8raw(w.y, 3);
        }
#pragma unroll
        for (int m = 8; m <= 32; m <<= 1) {
#pragma unroll
            for (int t = 0; t < 8; ++t) a[t] += __shfl_xor(a[t], m);
        }
        if (lane < 8) {
            uint4 rv = *(const uint4*)(r2 + (size_t)n * FOUT + l * 8);
            float4 o0, o1;
            o0.x = a[0] * 0x1p120f + bflo(rv.x); o0.y = a[1] * 0x1p120f + bfhi(rv.x);
            o0.z = a[2] * 0x1p120f + bflo(rv.y); o0.w = a[3] * 0x1p120f + bfhi(rv.y);
            o1.x = a[4] * 0x1p120f + bflo(rv.z); o1.y = a[5] * 0x1p120f + bfhi(rv.z);
            o1.z = a[6] * 0x1p120f + bflo(rv.w); o1.w = a[7] * 0x1p120f + bfhi(rv.w);
            float* op = out + (size_t)n * FOUT + l * 8;
            *(float4*)op = o0;
            *(float4*)(op + 4) = o1;
        }
    } else {
        int g = lane >> 4, l = lane & 15;
        float2 h = make_float2(0.f, 0.f);
        for (int k = e0 + g; k < e1; k += 4) {
            int s = adj[k];
            ushort2 uv = *(const ushort2*)(y + (size_t)s * FHID + l * 2);
            h.x += bf2f(uv.x); h.y += bf2f(uv.y);
        }
        h.x += __shfl_xor(h.x, 16); h.y += __shfl_xor(h.y, 16);
        h.x += __shfl_xor(h.x, 32); h.y += __shfl_xor(h.y, 32);
        const float* Wp = W2 + (size_t)dg * (FHID * FOUT) + lane;
        float acc = bf2f(r2[(size_t)n * FOUT + lane]);
#pragma unroll
        for (int f = 0; f < FHID; ++f) {
            float hf = __shfl((f & 1) ? h.y : h.x, f >> 1);
            acc += hf * Wp[f * FOUT];
        }
        out[(size_t)n * FOUT + lane] = acc;
    }
}

extern "C" void kernel_launch(void* const* d_in, const int* in_sizes, int n_in,
                              void* d_out, int out_size, void* d_ws, size_t ws_size,
                              hipStream_t stream) {
    const float* x   = (const float*)d_in[0];
    const int*   ei  = (const int*)d_in[1];   // int32, [2, E] flat
    const float* W1  = (const float*)d_in[2];
    const float* b1  = (const float*)d_in[3];
    const float* Wr1 = (const float*)d_in[4];
    const float* W2  = (const float*)d_in[5];
    const float* b2  = (const float*)d_in[6];
    const float* Wr2 = (const float*)d_in[7];

    int N = in_sizes[0] / FIN;
    int E = in_sizes[1] / 2;
    int NB = (N + 255) / 256;
    int K  = (N + 255) >> BSH;   // dst buckets

    char* ws = (char*)d_ws;
    size_t off = 0;
    auto alloc = [&](size_t bytes) {
        void* ptr = ws + off;
        off += (bytes + 511) / 512 * 512;
        return ptr;
    };
    int* deg              = (int*)alloc((size_t)N * sizeof(int));
    int* cursor           = (int*)alloc((size_t)N * sizeof(int));
    int* partial          = (int*)alloc((size_t)NB * sizeof(int));
    int* offsets          = (int*)alloc((size_t)NB * sizeof(int));
    int* gcur             = (int*)alloc((size_t)K * sizeof(int));
    int* adj              = (int*)alloc((size_t)E * sizeof(int));
    unsigned char*  z8    = (unsigned char*)alloc((size_t)N * FHID);
    unsigned short* r1    = (unsigned short*)alloc((size_t)N * FHID * 2);
    unsigned short* out1  = (unsigned short*)alloc((size_t)N * FHID * 2);
    unsigned char*  p8    = (unsigned char*)alloc((size_t)N * FOUT);
    unsigned short* r2    = (unsigned short*)alloc((size_t)N * FOUT * 2);
    unsigned short* wcat1 = (unsigned short*)alloc(64 * 128 * 2);
    unsigned short* wcat2 = (unsigned short*)alloc(128 * 32 * 2);
    // pairs (E*8B = 12.8MB) aliases [p8 | r2] (6.4 + 12.8 MB, contiguous):
    // both are dead until k_pre2m, which runs after k_passB consumes pairs.
    int2* pairs = (int2*)p8;

    float* out = (float*)d_out;

    hipMemsetAsync(deg, 0, (size_t)N * sizeof(int), stream);

    int eb = (E + 255) / 256;
    k_prepack<<<1, 256, 0, stream>>>(W1, Wr1, W2, Wr2, wcat1, wcat2);
    k_count<<<eb, 256, 0, stream>>>(ei, E, N, deg);
    k_blocksum<<<NB, 256, 0, stream>>>(deg, N, partial);
    k_scanpartial<<<1, 1024, 0, stream>>>(partial, NB, offsets);
    k_scandeg<<<NB, 256, 0, stream>>>(deg, N, offsets, cursor);
    k_initb<<<(K + 255) / 256, 256, 0, stream>>>(cursor, gcur, K);
    int nwgA = (E + ACHUNK - 1) / ACHUNK;
    k_passA<<<nwgA, 256, 0, stream>>>(ei, E, N, gcur, pairs);
    k_passB<<<K, 256, 0, stream>>>(pairs, gcur, cursor, adj, N);

    int nb64 = (N + 63) / 64;     // MFMA pre kernels: 64 nodes per block
    int nbfx = (N + 255) / 256;   // fixups: wave scans 64 nodes
    int nb_node = (N + 3) / 4;    // layer kernels: wave per node

    k_pre1m<<<nb64, 256, 0, stream>>>(x, wcat1, b1, z8, r1, N);
    k_fix1<<<nbfx, 256, 0, stream>>>(x, deg, b1, Wr1, r1, N);
    k_layer1b<<<nb_node, 256, 0, stream>>>(x, z8, r1, deg, cursor, adj, W1, out1, N);
    k_pre2m<<<nb64, 256, 0, stream>>>(out1, wcat2, b2, p8, r2, N);
    k_fix2<<<nbfx, 256, 0, stream>>>(out1, deg, b2, Wr2, r2, N);
    k_layer2b<<<nb_node, 256, 0, stream>>>(p8, r2, out1, deg, cursor, adj, W2, out, N);
}